// Round 12
// baseline (357.478 us; speedup 1.0000x reference)
//
#include <hip/hip_runtime.h>

typedef float f32x4 __attribute__((ext_vector_type(4)));

#define B_  512
#define T_  64
#define N_  30
#define FIN 512
#define D_  256
#define C_  7
#define NN  900

// ---------------- Kernel A: adj = mean_t(graph_sigs) ----------------
__global__ __launch_bounds__(256)
void adj_mean(const float* __restrict__ gs, float* __restrict__ adj)
{
    const int q  = blockIdx.x * 256 + threadIdx.x;   // 0..115199, exact
    const int b  = q / 225;
    const int qi = q - b * 225;
    const float* p = gs + (size_t)b * (T_ * NN) + qi * 4;
    f32x4 s = (f32x4){0.f, 0.f, 0.f, 0.f};
    #pragma unroll 8
    for (int t = 0; t < T_; ++t)
        s += *(const f32x4*)(p + t * NN);
    s *= (1.f / (float)T_);
    *(f32x4*)(adj + (size_t)b * NN + qi * 4) = s;
}

// ---------------- Kernel B: GEMM + conv-agg + pool + head + softmax ----------------
// R11 inner loop (measured: VGPR 52, no spill) at DOUBLE occupancy:
// 1024-thr block = 16 waves = 4 K-quarters (kq) x 2 overlapping row-groups (g)
// x 2 col-halves (cgrp). 2 blocks/CU -> 32 waves/CU = 8 waves/SIMD, so each
// chunk's ~500-900 cy load latency hides under 7 other waves' FMA issue.
// Lane: 8 rows x 4 cols x 128 K. acc = 8 x f32x4 = 32 VGPR.
__global__ __launch_bounds__(1024, 8)
void digcn_fused(const float* __restrict__ real,
                 const float* __restrict__ adj,
                 const float* __restrict__ W,
                 const float* __restrict__ conv_bias,
                 const float* __restrict__ pool_w,
                 const float* __restrict__ pool_b,
                 const float* __restrict__ head_w,
                 const float* __restrict__ head_b,
                 float* __restrict__ out)
{
    __shared__ __align__(16) float xwS[N_ * D_];     // 30720 B
    __shared__ __align__(16) float adjS[32 * 32];    // 4096 B, padded rows
    __shared__ float scoreS[4 * 32];
    __shared__ float sumS[32];
    __shared__ float logitS[8];

    const int tid  = threadIdx.x;
    const int b    = blockIdx.x;
    const int w    = tid >> 6;          // wave 0..15
    const int l    = tid & 63;
    const int kq   = w & 3;             // K-quarter: [kq*128, kq*128+128)
    const int g    = (w >> 2) & 1;      // row-group start g*14
    const int cgrp = w >> 3;            // col-half
    const int rh   = l >> 5;            // row sub-half
    const int r0   = g * 14 + rh * 8;   // 8 rows: {0,8,14,22} (max row 29)
    const int c0   = cgrp * 128 + (l & 31) * 4;

    const float* realb = real + (size_t)b * (N_ * FIN) + r0 * FIN + kq * 128;
    const float* adjb  = adj + (size_t)b * NN;
    const float* Wb    = W + (size_t)(kq * 128) * D_ + c0;

    // ---- stage adj into padded LDS (one element per thread); covered by
    //      the first combine barrier below ----
    {
        int i = tid >> 5, j = tid & 31;
        adjS[tid] = (i < N_ && j < N_) ? adjb[i * N_ + j] : 0.f;
    }

    f32x4 acc[8];
    #pragma unroll
    for (int rr = 0; rr < 8; ++rr) acc[rr] = (f32x4){0.f, 0.f, 0.f, 0.f};

    // ---- main loop: 32 chunks x 4 k; 128 v_fma vs 12 VMEM, 0 DS, 0 barriers ----
    for (int it = 0; it < 32; ++it) {
        const float* Wit = Wb + it * 4 * D_;
        f32x4 wv0 = *(const f32x4*)(Wit);
        f32x4 wv1 = *(const f32x4*)(Wit + D_);
        f32x4 wv2 = *(const f32x4*)(Wit + 2 * D_);
        f32x4 wv3 = *(const f32x4*)(Wit + 3 * D_);
        const float* rp = realb + it * 4;
        #pragma unroll
        for (int rr = 0; rr < 8; ++rr) {
            f32x4 rv = *(const f32x4*)(rp + rr * FIN);   // 2-addr broadcast
            acc[rr] += wv0 * rv[0];
            acc[rr] += wv1 * rv[1];
            acc[rr] += wv2 * rv[2];
            acc[rr] += wv3 * rv[3];
        }
    }

    // ---- staged K-quarter reduction into xwS (4 barriers, all threads reach) ----
    // step 0: rows 14,15 double-written bit-identically by g0/g1 waves of kq0.
    // steps 1-3: g1 skips rows 14,15 so the duplicate isn't added twice.
    #pragma unroll
    for (int step = 0; step < 4; ++step) {
        if (kq == step) {
            #pragma unroll
            for (int rr = 0; rr < 8; ++rr) {
                int row = r0 + rr;
                float* p = xwS + row * D_ + c0;
                if (step == 0) {
                    *(f32x4*)p = acc[rr];
                } else if (!(g == 1 && row < 16)) {
                    *(f32x4*)p = *(const f32x4*)p + acc[rr];
                }
            }
        }
        __syncthreads();
    }

    // ---- P3: agg = adj^T @ xw, ReLU, pool (threads 0..255, thread owns d) ----
    if (tid < D_) {
        float xcol[N_];
        #pragma unroll
        for (int i = 0; i < N_; ++i) xcol[i] = xwS[i * D_ + tid];   // lanes stride-1
        const float bias = conv_bias[tid];
        const float pw   = pool_w[tid];

        #pragma unroll
        for (int j0 = 0; j0 < N_ + 2; j0 += 4) {
            f32x4 agg = (f32x4){0.f, 0.f, 0.f, 0.f};
            #pragma unroll
            for (int i = 0; i < N_; ++i) {
                f32x4 a4 = *(const f32x4*)(adjS + i * 32 + j0);     // uniform broadcast
                agg += a4 * xcol[i];
            }
            #pragma unroll
            for (int c = 0; c < 4; ++c) {
                if (j0 + c < N_) {
                    float h = agg[c] + bias;
                    h = h > 0.f ? h : 0.f;
                    float v = h * pw;
                    #pragma unroll
                    for (int m = 32; m >= 1; m >>= 1) v += __shfl_xor(v, m, 64);
                    if (l == 0) scoreS[w * 32 + j0 + c] = v;
                }
            }
        }
    }
    __syncthreads();

    // ---- P4: combine waves, head matmul, softmax ----
    if (tid < N_)
        sumS[tid] = scoreS[tid] + scoreS[32 + tid] + scoreS[64 + tid] + scoreS[96 + tid]
                  + pool_b[0];
    __syncthreads();
    if (tid < C_) {
        float lg = head_b[tid];
        #pragma unroll
        for (int j = 0; j < N_; ++j) lg += sumS[j] * head_w[tid * N_ + j];
        logitS[tid] = lg;
    }
    __syncthreads();
    if (tid < C_) {
        float m = logitS[0];
        #pragma unroll
        for (int c = 1; c < C_; ++c) m = fmaxf(m, logitS[c]);
        float s = 0.f;
        #pragma unroll
        for (int c = 0; c < C_; ++c) s += expf(logitS[c] - m);
        out[b * C_ + tid] = expf(logitS[tid] - m) / s;
    }
}

extern "C" void kernel_launch(void* const* d_in, const int* in_sizes, int n_in,
                              void* d_out, int out_size, void* d_ws, size_t ws_size,
                              hipStream_t stream) {
    const float* real      = (const float*)d_in[0];
    // d_in[1] (imag) is unused by the forward pass
    const float* gs        = (const float*)d_in[2];
    const float* W         = (const float*)d_in[3];
    const float* conv_bias = (const float*)d_in[4];
    const float* pool_w    = (const float*)d_in[5];
    const float* pool_b    = (const float*)d_in[6];
    const float* head_w    = (const float*)d_in[7];
    const float* head_b    = (const float*)d_in[8];
    float* outp            = (float*)d_out;
    float* adjw            = (float*)d_ws;           // 512*900*4 = 1.84 MB

    adj_mean<<<dim3(450), dim3(256), 0, stream>>>(gs, adjw);
    digcn_fused<<<dim3(B_), dim3(1024), 0, stream>>>(
        real, adjw, W, conv_bias, pool_w, pool_b, head_w, head_b, outp);
}